// Round 1
// baseline (461.094 us; speedup 1.0000x reference)
//
#include <hip/hip_runtime.h>
#include <stdint.h>

typedef float f32x4 __attribute__((ext_vector_type(4)));
typedef __bf16 bf16x8 __attribute__((ext_vector_type(8)));

// RNE fp32->bf16 pair pack: one v_perm + 2x(add) per pair.
__device__ __forceinline__ unsigned int pack_bf16_rne(float fa, float fb) {
  unsigned int ua = __float_as_uint(fa);
  ua += 0x7fffu + ((ua >> 16) & 1u);
  unsigned int ub = __float_as_uint(fb);
  ub += 0x7fffu + ((ub >> 16) & 1u);
  // result bytes: [ub.3 ub.2 ua.3 ua.2] -> low16 = bf16(fa), high16 = bf16(fb)
  return __builtin_amdgcn_perm(ub, ua, 0x07060302u);
}

__device__ __forceinline__ void async_cp16(const void* g, void* l) {
  __builtin_amdgcn_global_load_lds(
      (const __attribute__((address_space(1))) unsigned int*)g,
      (__attribute__((address_space(3))) unsigned int*)l, 16, 0, 0);
}

// W fp32 [256,256] -> bf16 in workspace (128 KB)
__global__ void wcvt_kernel(const float* __restrict__ W, uint2* __restrict__ Wb) {
  int i = blockIdx.x * blockDim.x + threadIdx.x;  // 4 floats / thread
  float4 v = ((const float4*)W)[i];
  uint2 o;
  o.x = pack_bf16_rne(v.x, v.y);
  o.y = pack_bf16_rne(v.z, v.w);
  Wb[i] = o;
}

// Fused: log_map(x) @ W^T + b -> exp_map, 64 rows x 256 cols per block.
// As: [64][256] bf16 (unscaled x; log-map scale folded into epilogue).
// Bs: [256][64] bf16 per K-step.  Both XOR-swizzled: phys chunk = q ^ (row&7).
__global__ __launch_bounds__(256) void hyper_kernel(
    const float* __restrict__ x, const unsigned short* __restrict__ Wb,
    const float* __restrict__ bias, float* __restrict__ out) {
  __shared__ __align__(16) unsigned char As[64 * 256 * 2];   // 32 KB
  __shared__ __align__(16) unsigned char Bs[256 * 64 * 2];   // 32 KB
  __shared__ float a_scale[64];
  __shared__ float rowsq[64][4];
  __shared__ float oscale[64];

  const int tid = threadIdx.x;
  const int row0 = blockIdx.x * 64;

  // ---- Phase 1: read x once; row ssq + bf16 cvt into swizzled LDS ----
  {
    const int r = tid >> 2;  // 0..63
    const int j = tid & 3;   // 4 threads/row, 8 chunks (of 8 floats) each
    const float4* xr = (const float4*)(x + (size_t)(row0 + r) * 256);
    float ssq = 0.f;
#pragma unroll
    for (int i = 0; i < 8; ++i) {
      int q = j + 4 * i;  // logical chunk 0..31
      float4 v0 = xr[q * 2];
      float4 v1 = xr[q * 2 + 1];
      ssq += v0.x * v0.x + v0.y * v0.y + v0.z * v0.z + v0.w * v0.w +
             v1.x * v1.x + v1.y * v1.y + v1.z * v1.z + v1.w * v1.w;
      uint4 pk;
      pk.x = pack_bf16_rne(v0.x, v0.y);
      pk.y = pack_bf16_rne(v0.z, v0.w);
      pk.z = pack_bf16_rne(v1.x, v1.y);
      pk.w = pack_bf16_rne(v1.z, v1.w);
      *(uint4*)(As + r * 512 + ((q ^ (r & 7)) << 4)) = pk;
    }
    ssq += __shfl_xor(ssq, 1);
    ssq += __shfl_xor(ssq, 2);
    if (j == 0) {
      float xn = fmaxf(sqrtf(ssq), 1e-6f);
      float t = fminf(0.1f * xn, 1.f - 1e-6f);
      a_scale[r] = atanhf(t) / (0.1f * xn);  // log_map_zero row scale
    }
  }

  const int wv = tid >> 6;   // wave 0..3 -> cols wv*64..+63
  const int lane = tid & 63;
  const int l15 = lane & 15;
  const int l4 = lane >> 4;

  const f32x4 fzero = {0.f, 0.f, 0.f, 0.f};
  f32x4 acc[4][4];
#pragma unroll
  for (int a = 0; a < 4; ++a)
#pragma unroll
    for (int b = 0; b < 4; ++b) acc[a][b] = fzero;

  // ---- K loop: 4 steps of BK=64 ----
  for (int kb = 0; kb < 4; ++kb) {
    // stage B[256][64] bf16 from L2-resident Wb via global_load_lds(16B)
#pragma unroll
    for (int it = 0; it < 8; ++it) {
      int s = it * 256 + tid;           // slot: row = s>>3, phys chunk = s&7
      int rr = s >> 3, cc = s & 7;
      const unsigned short* g = Wb + rr * 256 + kb * 64 + ((cc ^ (rr & 7)) << 3);
      async_cp16(g, Bs + s * 16);
    }
    __syncthreads();  // drains vmcnt (B) and lgkm (phase-1 As writes)

#pragma unroll
    for (int kk = 0; kk < 2; ++kk) {
      bf16x8 af[4], bfr[4];
#pragma unroll
      for (int t = 0; t < 4; ++t) {
        int ar = t * 16 + l15;
        int qf = kb * 8 + kk * 4 + l4;  // logical chunk in full-K A row
        af[t] = *(const bf16x8*)(As + ar * 512 + ((qf ^ (ar & 7)) << 4));
        int br = wv * 64 + t * 16 + l15;
        int qb = kk * 4 + l4;           // logical chunk in B row
        bfr[t] = *(const bf16x8*)(Bs + br * 128 + ((qb ^ (br & 7)) << 4));
      }
#pragma unroll
      for (int tr = 0; tr < 4; ++tr)
#pragma unroll
        for (int tc = 0; tc < 4; ++tc)
          acc[tr][tc] = __builtin_amdgcn_mfma_f32_16x16x32_bf16(
              af[tr], bfr[tc], acc[tr][tc], 0, 0, 0);
    }
    __syncthreads();  // Bs reused next kb
  }

  // ---- Epilogue: v = a_scale[m]*acc + b[n]; exp_map row scale; store ----
  float bv[4];
#pragma unroll
  for (int tc = 0; tc < 4; ++tc) bv[tc] = bias[wv * 64 + tc * 16 + l15];

  float p[4][4];
#pragma unroll
  for (int tr = 0; tr < 4; ++tr) {
#pragma unroll
    for (int rg = 0; rg < 4; ++rg) {
      int lr = tr * 16 + l4 * 4 + rg;  // local row (C/D layout, m89-verified)
      float as = a_scale[lr];
      float s = 0.f;
#pragma unroll
      for (int tc = 0; tc < 4; ++tc) {
        float v = acc[tr][tc][rg] * as + bv[tc];
        acc[tr][tc][rg] = v;
        s += v * v;
      }
      // reduce over the 16 lanes (cols) of this row within the wave
      s += __shfl_xor(s, 1);
      s += __shfl_xor(s, 2);
      s += __shfl_xor(s, 4);
      s += __shfl_xor(s, 8);
      p[tr][rg] = s;
    }
  }
  if (l15 == 0) {
#pragma unroll
    for (int tr = 0; tr < 4; ++tr)
#pragma unroll
      for (int rg = 0; rg < 4; ++rg)
        rowsq[tr * 16 + l4 * 4 + rg][wv] = p[tr][rg];
  }
  __syncthreads();
  if (tid < 64) {
    float ssq = rowsq[tid][0] + rowsq[tid][1] + rowsq[tid][2] + rowsq[tid][3];
    float norm = sqrtf(ssq);
    float vn = fmaxf(norm, 1e-6f);
    float a1 = tanhf(0.1f * vn) / (0.1f * vn);       // exp_map scale
    float rn = fmaxf(norm * a1, 1e-6f);              // ||res||
    float cl = fminf(rn, 10.0f - 2e-6f);             // project_to_ball
    oscale[tid] = a1 * (cl / rn);
  }
  __syncthreads();

#pragma unroll
  for (int tr = 0; tr < 4; ++tr)
#pragma unroll
    for (int tc = 0; tc < 4; ++tc)
#pragma unroll
      for (int rg = 0; rg < 4; ++rg) {
        int lr = tr * 16 + l4 * 4 + rg;
        out[(size_t)(row0 + lr) * 256 + wv * 64 + tc * 16 + l15] =
            acc[tr][tc][rg] * oscale[lr];
      }
}

extern "C" void kernel_launch(void* const* d_in, const int* in_sizes, int n_in,
                              void* d_out, int out_size, void* d_ws, size_t ws_size,
                              hipStream_t stream) {
  const float* x = (const float*)d_in[0];
  const float* W = (const float*)d_in[1];
  const float* bias = (const float*)d_in[2];
  float* out = (float*)d_out;
  const int N = in_sizes[0] / 256;        // 262144 rows (divisible by 64)
  const int wgrid = in_sizes[1] / 1024;   // 65536 / (256 thr * 4 elem) = 64

  wcvt_kernel<<<wgrid, 256, 0, stream>>>(W, (uint2*)d_ws);
  hyper_kernel<<<N / 64, 256, 0, stream>>>(x, (const unsigned short*)d_ws, bias, out);
}